// Round 2
// baseline (1355.123 us; speedup 1.0000x reference)
//
#include <hip/hip_runtime.h>
#include <hip/hip_bf16.h>
#include <stdint.h>

#define DD 512
#define HW 9216
#define NBATCH 8
#define BN_EPS 1e-5f

typedef __attribute__((ext_vector_type(8))) short short8;
typedef __attribute__((ext_vector_type(4))) float f32x4;

__device__ __forceinline__ unsigned short f2bf(float f) {
  union { float f; uint32_t u; } v; v.f = f;
  uint32_t r = v.u + 0x7FFFu + ((v.u >> 16) & 1u);   // RNE
  return (unsigned short)(r >> 16);
}
__device__ __forceinline__ float bf2f(unsigned short u) {
  union { uint32_t u; float f; } v; v.u = ((uint32_t)u) << 16;
  return v.f;
}

// ---------------- prep: bf16 weights + folded BN ----------------
__global__ void prep_kernel(const float* __restrict__ W1, const float* __restrict__ W2,
                            const float* __restrict__ s1, const float* __restrict__ b1,
                            const float* __restrict__ m1, const float* __restrict__ v1,
                            const float* __restrict__ s2, const float* __restrict__ b2,
                            const float* __restrict__ m2, const float* __restrict__ v2,
                            unsigned short* __restrict__ W1b, unsigned short* __restrict__ W2b,
                            float* __restrict__ sc1, float* __restrict__ sh1,
                            float* __restrict__ sc2, float* __restrict__ sh2) {
  int t = blockIdx.x * 256 + threadIdx.x;
  if (t < DD * DD) { W1b[t] = f2bf(W1[t]); W2b[t] = f2bf(W2[t]); }
  if (t < DD) {
    float a = s1[t] * rsqrtf(v1[t] + BN_EPS);
    sc1[t] = a; sh1[t] = b1[t] - m1[t] * a;
    float c = s2[t] * rsqrtf(v2[t] + BN_EPS);
    sc2[t] = c; sh2[t] = b2[t] - m2[t] * c;
  }
}

// ---------------- GEMM + BN + ReLU (bf16 MFMA, 128x128 tile, BK=32) ---------
// Y[b,e,n] = relu(scale[e] * sum_d W[e,d]*X[b,d,n] + shift[e]), Y in bf16.
template <int TIN_BF16>
__global__ __launch_bounds__(256) void gemm_bn(
    const void* __restrict__ Xin_, const unsigned short* __restrict__ Wb,
    const float* __restrict__ scale, const float* __restrict__ shift,
    unsigned short* __restrict__ Yout) {
  const int b  = blockIdx.z;
  const int e0 = blockIdx.y * 128;
  const int n0 = blockIdx.x * 128;
  const int tid  = threadIdx.x;
  const int lane = tid & 63;
  const int wave = tid >> 6;
  const int wr = wave >> 1, wc = wave & 1;     // wave -> 64x64 quadrant

  __shared__ __align__(16) unsigned short Alds[128 * 32];   // [e_row][k], 64B rows
  __shared__ __align__(16) unsigned short Blds[128 * 40];   // [n_col][k], 80B rows (padded)

  const float* Xf          = (const float*)Xin_ + (size_t)b * DD * HW;
  const unsigned short* Xh = (const unsigned short*)Xin_ + (size_t)b * DD * HW;

  f32x4 acc[4][4];
#pragma unroll
  for (int i = 0; i < 4; i++)
#pragma unroll
    for (int j = 0; j < 4; j++) acc[i][j] = (f32x4)0.0f;

  const int arow  = tid >> 1;       // 0..127
  const int ahalf = tid & 1;        // which 16-elem half of the 32-wide k row
  const int bcol  = tid & 127;      // 0..127 (n within tile)
  const int bdh   = tid >> 7;       // 0..1 (16-wide d block)

  const int koff = (lane >> 4) * 8; // fragment k offset (8 contiguous k per lane)
  const int lrow = lane & 15;

  for (int kt = 0; kt < DD / 32; ++kt) {
    const int d0 = kt * 32;
    __syncthreads();   // previous iter's frag reads done before overwrite

    // --- stage A: W rows (already bf16), linear [row][k] ---
    {
      const unsigned short* src = Wb + (size_t)(e0 + arow) * DD + d0 + ahalf * 16;
      short8 v0 = *(const short8*)(src);
      short8 v1 = *(const short8*)(src + 8);
      *(short8*)&Alds[arow * 32 + ahalf * 16]     = v0;
      *(short8*)&Alds[arow * 32 + ahalf * 16 + 8] = v1;
    }
    // --- stage B: transpose X[d][n] -> Blds[n][d], convert to bf16 ---
    {
      unsigned short* dst = &Blds[bcol * 40 + bdh * 16];
      if (TIN_BF16) {
        const unsigned short* src = Xh + (size_t)(d0 + bdh * 16) * HW + n0 + bcol;
#pragma unroll
        for (int j = 0; j < 8; j++) {
          uint32_t u0 = src[(size_t)(2 * j) * HW];
          uint32_t u1 = src[(size_t)(2 * j + 1) * HW];
          *(uint32_t*)&dst[2 * j] = u0 | (u1 << 16);
        }
      } else {
        const float* src = Xf + (size_t)(d0 + bdh * 16) * HW + n0 + bcol;
#pragma unroll
        for (int j = 0; j < 8; j++) {
          uint32_t u0 = f2bf(src[(size_t)(2 * j) * HW]);
          uint32_t u1 = f2bf(src[(size_t)(2 * j + 1) * HW]);
          *(uint32_t*)&dst[2 * j] = u0 | (u1 << 16);
        }
      }
    }
    __syncthreads();

    // --- fragments + MFMA ---
    short8 af[4], bfr[4];
#pragma unroll
    for (int ma = 0; ma < 4; ma++)
      af[ma] = *(const short8*)&Alds[(wr * 64 + ma * 16 + lrow) * 32 + koff];
#pragma unroll
    for (int nb = 0; nb < 4; nb++)
      bfr[nb] = *(const short8*)&Blds[(wc * 64 + nb * 16 + lrow) * 40 + koff];
#pragma unroll
    for (int ma = 0; ma < 4; ma++)
#pragma unroll
      for (int nb = 0; nb < 4; nb++)
        acc[ma][nb] = __builtin_amdgcn_mfma_f32_16x16x32_bf16(af[ma], bfr[nb], acc[ma][nb], 0, 0, 0);
  }

  // --- epilogue: BN fold + ReLU + bf16 store ---
  const int rbase = (lane >> 4) * 4;
  const int col   = lane & 15;
#pragma unroll
  for (int ma = 0; ma < 4; ma++) {
    const int ebase = e0 + wr * 64 + ma * 16 + rbase;
    float sc[4], sh[4];
#pragma unroll
    for (int r = 0; r < 4; r++) { sc[r] = scale[ebase + r]; sh[r] = shift[ebase + r]; }
#pragma unroll
    for (int nb = 0; nb < 4; nb++) {
      const int n = n0 + wc * 64 + nb * 16 + col;
      const size_t base = (size_t)b * DD * HW + (size_t)ebase * HW + n;
#pragma unroll
      for (int r = 0; r < 4; r++) {
        float y = acc[ma][nb][r] * sc[r] + sh[r];
        y = y > 0.f ? y : 0.f;
        Yout[base + (size_t)r * HW] = f2bf(y);
      }
    }
  }
}

// ---------------- soft-VQ x3 + final add (fp32 VALU) ----------------
__global__ __launch_bounds__(64) void vq_kernel(
    const float* __restrict__ X, const unsigned short* __restrict__ X2,
    const unsigned short* __restrict__ X3,
    const float* __restrict__ cw1, const float* __restrict__ cw2,
    const float* __restrict__ cw3,
    const float* __restrict__ g1, const float* __restrict__ g2,
    const float* __restrict__ g3, float* __restrict__ out) {
  const int p = blockIdx.x * 64 + threadIdx.x;     // 0..73727
  const size_t base = (size_t)(p / HW) * DD * HW + (size_t)(p % HW);

  float l1[16], l2[32], l3[64];
#pragma unroll
  for (int k = 0; k < 16; k++) l1[k] = 0.f;
#pragma unroll
  for (int k = 0; k < 32; k++) l2[k] = 0.f;
#pragma unroll
  for (int k = 0; k < 64; k++) l3[k] = 0.f;

  for (int d = 0; d < DD; ++d) {
    const float xv  = X[base + (size_t)d * HW];
    const float x2v = bf2f(X2[base + (size_t)d * HW]);
    const float x3v = bf2f(X3[base + (size_t)d * HW]);
#pragma unroll
    for (int k = 0; k < 16; k++) l1[k] = fmaf(xv,  cw1[d * 16 + k], l1[k]);
#pragma unroll
    for (int k = 0; k < 32; k++) l2[k] = fmaf(x2v, cw2[d * 32 + k], l2[k]);
#pragma unroll
    for (int k = 0; k < 64; k++) l3[k] = fmaf(x3v, cw3[d * 64 + k], l3[k]);
  }

  // softmax per codebook, fold gamma/sum into the probabilities
  {
    float m = l1[0], s = 0.f;
#pragma unroll
    for (int k = 1; k < 16; k++) m = fmaxf(m, l1[k]);
#pragma unroll
    for (int k = 0; k < 16; k++) { l1[k] = __expf(l1[k] - m); s += l1[k]; }
    const float inv = g1[0] / s;
#pragma unroll
    for (int k = 0; k < 16; k++) l1[k] *= inv;
  }
  {
    float m = l2[0], s = 0.f;
#pragma unroll
    for (int k = 1; k < 32; k++) m = fmaxf(m, l2[k]);
#pragma unroll
    for (int k = 0; k < 32; k++) { l2[k] = __expf(l2[k] - m); s += l2[k]; }
    const float inv = g2[0] / s;
#pragma unroll
    for (int k = 0; k < 32; k++) l2[k] *= inv;
  }
  {
    float m = l3[0], s = 0.f;
#pragma unroll
    for (int k = 1; k < 64; k++) m = fmaxf(m, l3[k]);
#pragma unroll
    for (int k = 0; k < 64; k++) { l3[k] = __expf(l3[k] - m); s += l3[k]; }
    const float inv = g3[0] / s;
#pragma unroll
    for (int k = 0; k < 64; k++) l3[k] *= inv;
  }

  // reconstruction + residual add
  for (int d = 0; d < DD; ++d) {
    float e = 0.f;
#pragma unroll
    for (int k = 0; k < 16; k++) e = fmaf(l1[k], cw1[d * 16 + k], e);
#pragma unroll
    for (int k = 0; k < 32; k++) e = fmaf(l2[k], cw2[d * 32 + k], e);
#pragma unroll
    for (int k = 0; k < 64; k++) e = fmaf(l3[k], cw3[d * 64 + k], e);
    out[base + (size_t)d * HW] = X[base + (size_t)d * HW] + e;
  }
}

extern "C" void kernel_launch(void* const* d_in, const int* in_sizes, int n_in,
                              void* d_out, int out_size, void* d_ws, size_t ws_size,
                              hipStream_t stream) {
  const float* X    = (const float*)d_in[0];
  const float* W1   = (const float*)d_in[1];
  const float* bn1s = (const float*)d_in[2];
  const float* bn1b = (const float*)d_in[3];
  const float* bn1m = (const float*)d_in[4];
  const float* bn1v = (const float*)d_in[5];
  const float* W2   = (const float*)d_in[6];
  const float* bn2s = (const float*)d_in[7];
  const float* bn2b = (const float*)d_in[8];
  const float* bn2m = (const float*)d_in[9];
  const float* bn2v = (const float*)d_in[10];
  const float* cw1  = (const float*)d_in[11];
  const float* cw2  = (const float*)d_in[12];
  const float* cw3  = (const float*)d_in[13];
  const float* g1   = (const float*)d_in[14];
  const float* g2   = (const float*)d_in[15];
  const float* g3   = (const float*)d_in[16];

  // ws layout (needs ~146 MB): W1b(512KB) W2b(512KB) scales(8KB) | X2(72MB) X3(72MB)
  char* ws = (char*)d_ws;
  unsigned short* W1b = (unsigned short*)(ws);
  unsigned short* W2b = (unsigned short*)(ws + 524288);
  float* sc1 = (float*)(ws + 1048576);
  float* sh1 = sc1 + 512;
  float* sc2 = sh1 + 512;
  float* sh2 = sc2 + 512;
  unsigned short* X2 = (unsigned short*)(ws + (1 << 21));
  unsigned short* X3 = X2 + (size_t)NBATCH * DD * HW;

  prep_kernel<<<1024, 256, 0, stream>>>(W1, W2, bn1s, bn1b, bn1m, bn1v,
                                        bn2s, bn2b, bn2m, bn2v,
                                        W1b, W2b, sc1, sh1, sc2, sh2);

  dim3 gg(HW / 128, DD / 128, NBATCH);   // (72, 4, 8)
  gemm_bn<0><<<gg, 256, 0, stream>>>((const void*)X,  W1b, sc1, sh1, X2);
  gemm_bn<1><<<gg, 256, 0, stream>>>((const void*)X2, W2b, sc2, sh2, X3);

  vq_kernel<<<73728 / 64, 64, 0, stream>>>(X, X2, X3, cw1, cw2, cw3,
                                           g1, g2, g3, (float*)d_out);
}

// Round 3
// 329.487 us; speedup vs baseline: 4.1128x; 4.1128x over previous
//
#include <hip/hip_runtime.h>
#include <hip/hip_bf16.h>
#include <stdint.h>

#define DD 512
#define HW 9216
#define NBATCH 8
#define BN_EPS 1e-5f

typedef __attribute__((ext_vector_type(8))) short short8;
typedef __attribute__((ext_vector_type(4))) float f32x4;

__device__ __forceinline__ unsigned short f2bf(float f) {
  union { float f; uint32_t u; } v; v.f = f;
  uint32_t r = v.u + 0x7FFFu + ((v.u >> 16) & 1u);   // RNE
  return (unsigned short)(r >> 16);
}

// ---------------- prep: bf16 weights + folded BN ----------------
__global__ void prep_kernel(const float* __restrict__ W1, const float* __restrict__ W2,
                            const float* __restrict__ s1, const float* __restrict__ b1,
                            const float* __restrict__ m1, const float* __restrict__ v1,
                            const float* __restrict__ s2, const float* __restrict__ b2,
                            const float* __restrict__ m2, const float* __restrict__ v2,
                            unsigned short* __restrict__ W1b, unsigned short* __restrict__ W2b,
                            float* __restrict__ sc1, float* __restrict__ sh1,
                            float* __restrict__ sc2, float* __restrict__ sh2) {
  int t = blockIdx.x * 256 + threadIdx.x;
  if (t < DD * DD) { W1b[t] = f2bf(W1[t]); W2b[t] = f2bf(W2[t]); }
  if (t < DD) {
    float a = s1[t] * rsqrtf(v1[t] + BN_EPS);
    sc1[t] = a; sh1[t] = b1[t] - m1[t] * a;
    float c = s2[t] * rsqrtf(v2[t] + BN_EPS);
    sc2[t] = c; sh2[t] = b2[t] - m2[t] * c;
  }
}

// prep codebooks: CWt[112][512] (transposed concat), CWc[512][128] (native concat, 0-pad)
__global__ void prep_cw(const float* __restrict__ cw1, const float* __restrict__ cw2,
                        const float* __restrict__ cw3,
                        unsigned short* __restrict__ CWt, unsigned short* __restrict__ CWc) {
  int t = blockIdx.x * 256 + threadIdx.x;   // 65536 total
  int d = t >> 7, k = t & 127;
  float v = 0.f;
  if (k < 16) v = cw1[d * 16 + k];
  else if (k < 48) v = cw2[d * 32 + (k - 16)];
  else if (k < 112) v = cw3[d * 64 + (k - 48)];
  unsigned short bv = f2bf(v);
  CWc[d * 128 + k] = bv;
  if (k < 112) CWt[k * 512 + d] = bv;
}

// ---------------- GEMM + BN + ReLU (bf16 MFMA, 128x128 tile, BK=32) ---------
template <int TIN_BF16>
__global__ __launch_bounds__(256) void gemm_bn(
    const void* __restrict__ Xin_, const unsigned short* __restrict__ Wb,
    const float* __restrict__ scale, const float* __restrict__ shift,
    unsigned short* __restrict__ Yout) {
  const int b  = blockIdx.z;
  const int e0 = blockIdx.y * 128;
  const int n0 = blockIdx.x * 128;
  const int tid  = threadIdx.x;
  const int lane = tid & 63;
  const int wave = tid >> 6;
  const int wr = wave >> 1, wc = wave & 1;

  __shared__ __align__(16) unsigned short Alds[128 * 32];
  __shared__ __align__(16) unsigned short Blds[128 * 40];

  const float* Xf          = (const float*)Xin_ + (size_t)b * DD * HW;
  const unsigned short* Xh = (const unsigned short*)Xin_ + (size_t)b * DD * HW;

  f32x4 acc[4][4];
#pragma unroll
  for (int i = 0; i < 4; i++)
#pragma unroll
    for (int j = 0; j < 4; j++) acc[i][j] = (f32x4)0.0f;

  const int arow  = tid >> 1;
  const int ahalf = tid & 1;
  const int bcol  = tid & 127;
  const int bdh   = tid >> 7;

  const int koff = (lane >> 4) * 8;
  const int lrow = lane & 15;

  for (int kt = 0; kt < DD / 32; ++kt) {
    const int d0 = kt * 32;
    __syncthreads();
    {
      const unsigned short* src = Wb + (size_t)(e0 + arow) * DD + d0 + ahalf * 16;
      short8 v0 = *(const short8*)(src);
      short8 v1 = *(const short8*)(src + 8);
      *(short8*)&Alds[arow * 32 + ahalf * 16]     = v0;
      *(short8*)&Alds[arow * 32 + ahalf * 16 + 8] = v1;
    }
    {
      unsigned short* dst = &Blds[bcol * 40 + bdh * 16];
      if (TIN_BF16) {
        const unsigned short* src = Xh + (size_t)(d0 + bdh * 16) * HW + n0 + bcol;
#pragma unroll
        for (int j = 0; j < 8; j++) {
          uint32_t u0 = src[(size_t)(2 * j) * HW];
          uint32_t u1 = src[(size_t)(2 * j + 1) * HW];
          *(uint32_t*)&dst[2 * j] = u0 | (u1 << 16);
        }
      } else {
        const float* src = Xf + (size_t)(d0 + bdh * 16) * HW + n0 + bcol;
#pragma unroll
        for (int j = 0; j < 8; j++) {
          uint32_t u0 = f2bf(src[(size_t)(2 * j) * HW]);
          uint32_t u1 = f2bf(src[(size_t)(2 * j + 1) * HW]);
          *(uint32_t*)&dst[2 * j] = u0 | (u1 << 16);
        }
      }
    }
    __syncthreads();

    short8 af[4], bfr[4];
#pragma unroll
    for (int ma = 0; ma < 4; ma++)
      af[ma] = *(const short8*)&Alds[(wr * 64 + ma * 16 + lrow) * 32 + koff];
#pragma unroll
    for (int nb = 0; nb < 4; nb++)
      bfr[nb] = *(const short8*)&Blds[(wc * 64 + nb * 16 + lrow) * 40 + koff];
#pragma unroll
    for (int ma = 0; ma < 4; ma++)
#pragma unroll
      for (int nb = 0; nb < 4; nb++)
        acc[ma][nb] = __builtin_amdgcn_mfma_f32_16x16x32_bf16(af[ma], bfr[nb], acc[ma][nb], 0, 0, 0);
  }

  const int rbase = (lane >> 4) * 4;
  const int col   = lane & 15;
#pragma unroll
  for (int ma = 0; ma < 4; ma++) {
    const int ebase = e0 + wr * 64 + ma * 16 + rbase;
    float sc[4], sh[4];
#pragma unroll
    for (int r = 0; r < 4; r++) { sc[r] = scale[ebase + r]; sh[r] = shift[ebase + r]; }
#pragma unroll
    for (int nb = 0; nb < 4; nb++) {
      const int n = n0 + wc * 64 + nb * 16 + col;
      const size_t base = (size_t)b * DD * HW + (size_t)ebase * HW + n;
#pragma unroll
      for (int r = 0; r < 4; r++) {
        float y = acc[ma][nb][r] * sc[r] + sh[r];
        y = y > 0.f ? y : 0.f;
        Yout[base + (size_t)r * HW] = f2bf(y);
      }
    }
  }
}

// ---------------- fused soft-VQ x3 via MFMA + final add ----------------
// Block: 64 positions (one batch), 4 waves. Phase 1: logits L[64 x 112] by MFMA.
// Phase 2: in-register softmax (16-lane shfl groups), P' -> LDS [64][128] bf16.
// Phase 3: E = CWc @ P'^T (M=d, N=pos, k=128), fused X + E store.
__global__ __launch_bounds__(256) void vq_mfma(
    const float* __restrict__ X, const unsigned short* __restrict__ X2,
    const unsigned short* __restrict__ X3,
    const unsigned short* __restrict__ CWt,   // [112][512]
    const unsigned short* __restrict__ CWc,   // [512][128]
    const float* __restrict__ gg1, const float* __restrict__ gg2,
    const float* __restrict__ gg3, float* __restrict__ out) {
  const int b  = blockIdx.y;
  const int n0 = blockIdx.x * 64;
  const int tid  = threadIdx.x;
  const int lane = tid & 63;
  const int wv   = tid >> 6;
  const int hi = lane >> 4, lr = lane & 15;

  __shared__ __align__(16) unsigned short Pl[64 * 136];   // P' [pos][code], pad 136
  __shared__ __align__(16) unsigned short Stg[17408];     // ph1: 3x[64][40] + [112][40]; ph3: [128][136]

  const size_t bbase = (size_t)b * DD * HW;

  f32x4 accl[7];
#pragma unroll
  for (int t = 0; t < 7; t++) accl[t] = (f32x4)0.0f;

  const int sn = tid & 63;     // staged position
  const int sg = tid >> 6;     // d-group (8 d each)

  // ---------- phase 1: logits ----------
  for (int kt = 0; kt < 16; ++kt) {
    const int d0 = kt * 32;
    __syncthreads();
    {  // X (fp32 -> bf16), transpose to [pos][d]
      const float* src = X + bbase + (size_t)(d0 + sg * 8) * HW + n0 + sn;
      unsigned short* dst = &Stg[sn * 40 + sg * 8];
#pragma unroll
      for (int j = 0; j < 4; j++) {
        uint32_t u0 = f2bf(src[(size_t)(2 * j) * HW]);
        uint32_t u1 = f2bf(src[(size_t)(2 * j + 1) * HW]);
        *(uint32_t*)&dst[2 * j] = u0 | (u1 << 16);
      }
    }
    {  // X2
      const unsigned short* src = X2 + bbase + (size_t)(d0 + sg * 8) * HW + n0 + sn;
      unsigned short* dst = &Stg[2560 + sn * 40 + sg * 8];
#pragma unroll
      for (int j = 0; j < 4; j++) {
        uint32_t u0 = src[(size_t)(2 * j) * HW];
        uint32_t u1 = src[(size_t)(2 * j + 1) * HW];
        *(uint32_t*)&dst[2 * j] = u0 | (u1 << 16);
      }
    }
    {  // X3
      const unsigned short* src = X3 + bbase + (size_t)(d0 + sg * 8) * HW + n0 + sn;
      unsigned short* dst = &Stg[5120 + sn * 40 + sg * 8];
#pragma unroll
      for (int j = 0; j < 4; j++) {
        uint32_t u0 = src[(size_t)(2 * j) * HW];
        uint32_t u1 = src[(size_t)(2 * j + 1) * HW];
        *(uint32_t*)&dst[2 * j] = u0 | (u1 << 16);
      }
    }
    {  // CWt chunk [112][32] -> Stg[7680 + row*40 + c]
#pragma unroll
      for (int u = tid; u < 1792; u += 256) {
        int row = u >> 4, c = u & 15;
        uint32_t v = *(const uint32_t*)&CWt[row * 512 + d0 + c * 2];
        *(uint32_t*)&Stg[7680 + row * 40 + c * 2] = v;
      }
    }
    __syncthreads();

    short8 a0 = *(const short8*)&Stg[(wv * 16 + lr) * 40 + hi * 8];
    short8 a1 = *(const short8*)&Stg[2560 + (wv * 16 + lr) * 40 + hi * 8];
    short8 a2 = *(const short8*)&Stg[5120 + (wv * 16 + lr) * 40 + hi * 8];
    short8 bt[7];
#pragma unroll
    for (int t = 0; t < 7; t++)
      bt[t] = *(const short8*)&Stg[7680 + (t * 16 + lr) * 40 + hi * 8];
    accl[0] = __builtin_amdgcn_mfma_f32_16x16x32_bf16(a0, bt[0], accl[0], 0, 0, 0);
    accl[1] = __builtin_amdgcn_mfma_f32_16x16x32_bf16(a1, bt[1], accl[1], 0, 0, 0);
    accl[2] = __builtin_amdgcn_mfma_f32_16x16x32_bf16(a1, bt[2], accl[2], 0, 0, 0);
#pragma unroll
    for (int t = 3; t < 7; t++)
      accl[t] = __builtin_amdgcn_mfma_f32_16x16x32_bf16(a2, bt[t], accl[t], 0, 0, 0);
  }

  // ---------- phase 2: softmax (lane holds pos = wv*16+4*hi+r, code = 16t+lr) ----
  {
    const float gv1 = gg1[0], gv2 = gg2[0], gv3 = gg3[0];
    float p[7][4];
#pragma unroll
    for (int r = 0; r < 4; ++r) {
      {  // cb1: tile 0
        float v = accl[0][r];
        float m = v;
#pragma unroll
        for (int mk = 1; mk <= 8; mk <<= 1) m = fmaxf(m, __shfl_xor(m, mk, 64));
        float e = __expf(v - m);
        float s = e;
#pragma unroll
        for (int mk = 1; mk <= 8; mk <<= 1) s += __shfl_xor(s, mk, 64);
        p[0][r] = e * (gv1 / s);
      }
      {  // cb2: tiles 1,2
        float v1 = accl[1][r], v2 = accl[2][r];
        float m = fmaxf(v1, v2);
#pragma unroll
        for (int mk = 1; mk <= 8; mk <<= 1) m = fmaxf(m, __shfl_xor(m, mk, 64));
        float e1 = __expf(v1 - m), e2 = __expf(v2 - m);
        float s = e1 + e2;
#pragma unroll
        for (int mk = 1; mk <= 8; mk <<= 1) s += __shfl_xor(s, mk, 64);
        float sc = gv2 / s;
        p[1][r] = e1 * sc; p[2][r] = e2 * sc;
      }
      {  // cb3: tiles 3..6
        float m = fmaxf(fmaxf(accl[3][r], accl[4][r]), fmaxf(accl[5][r], accl[6][r]));
#pragma unroll
        for (int mk = 1; mk <= 8; mk <<= 1) m = fmaxf(m, __shfl_xor(m, mk, 64));
        float e[4], s = 0.f;
#pragma unroll
        for (int t = 0; t < 4; t++) { e[t] = __expf(accl[3 + t][r] - m); s += e[t]; }
#pragma unroll
        for (int mk = 1; mk <= 8; mk <<= 1) s += __shfl_xor(s, mk, 64);
        float sc = gv3 / s;
#pragma unroll
        for (int t = 0; t < 4; t++) p[3 + t][r] = e[t] * sc;
      }
    }
    const int posr = wv * 16 + 4 * hi;
#pragma unroll
    for (int t = 0; t < 7; ++t)
#pragma unroll
      for (int r = 0; r < 4; ++r)
        Pl[(posr + r) * 136 + t * 16 + lr] = f2bf(p[t][r]);
    // zero pad codes 112..127
    {
      int pp = tid & 63, cg = tid >> 6;
#pragma unroll
      for (int i = 0; i < 4; ++i) Pl[pp * 136 + 112 + cg * 4 + i] = 0;
    }
  }
  __syncthreads();

  // ---------- phase 3: E = CWc @ P'^T, fused X + E ----------
  short8 pf[4][4];
#pragma unroll
  for (int ct = 0; ct < 4; ++ct)
#pragma unroll
    for (int s = 0; s < 4; ++s)
      pf[ct][s] = *(const short8*)&Pl[(ct * 16 + lr) * 136 + s * 32 + hi * 8];

  const float* Xg = X + bbase;
  float* outg = out + bbase;
  for (int chunk = 0; chunk < 4; ++chunk) {
    __syncthreads();
    {  // stage CWc rows [chunk*128 .. +128) -> Stg[row*136 + k]
      int row = tid >> 1, half = tid & 1;
      const unsigned short* src = CWc + (size_t)(chunk * 128 + row) * 128 + half * 64;
      unsigned short* dst = &Stg[row * 136 + half * 64];
#pragma unroll
      for (int i = 0; i < 8; ++i)
        *(short8*)(dst + i * 8) = *(const short8*)(src + i * 8);
    }
    __syncthreads();
#pragma unroll
    for (int dl = wv; dl < 8; dl += 4) {
      f32x4 acc[4];
#pragma unroll
      for (int ct = 0; ct < 4; ++ct) acc[ct] = (f32x4)0.0f;
#pragma unroll
      for (int s = 0; s < 4; ++s) {
        short8 af = *(const short8*)&Stg[(dl * 16 + lr) * 136 + s * 32 + hi * 8];
#pragma unroll
        for (int ct = 0; ct < 4; ++ct)
          acc[ct] = __builtin_amdgcn_mfma_f32_16x16x32_bf16(af, pf[ct][s], acc[ct], 0, 0, 0);
      }
      const int dgb = chunk * 128 + dl * 16 + 4 * hi;
#pragma unroll
      for (int ct = 0; ct < 4; ++ct) {
        const int n = n0 + ct * 16 + lr;
#pragma unroll
        for (int r = 0; r < 4; ++r) {
          const size_t a = (size_t)(dgb + r) * HW + n;
          outg[a] = Xg[a] + acc[ct][r];
        }
      }
    }
  }
}

extern "C" void kernel_launch(void* const* d_in, const int* in_sizes, int n_in,
                              void* d_out, int out_size, void* d_ws, size_t ws_size,
                              hipStream_t stream) {
  const float* X    = (const float*)d_in[0];
  const float* W1   = (const float*)d_in[1];
  const float* bn1s = (const float*)d_in[2];
  const float* bn1b = (const float*)d_in[3];
  const float* bn1m = (const float*)d_in[4];
  const float* bn1v = (const float*)d_in[5];
  const float* W2   = (const float*)d_in[6];
  const float* bn2s = (const float*)d_in[7];
  const float* bn2b = (const float*)d_in[8];
  const float* bn2m = (const float*)d_in[9];
  const float* bn2v = (const float*)d_in[10];
  const float* cw1  = (const float*)d_in[11];
  const float* cw2  = (const float*)d_in[12];
  const float* cw3  = (const float*)d_in[13];
  const float* g1   = (const float*)d_in[14];
  const float* g2   = (const float*)d_in[15];
  const float* g3   = (const float*)d_in[16];

  // ws: W1b(512K) | W2b(512K) | scales(8K) | CWt(112K) | CWc(128K) | X2(72M) | X3(72M)
  char* ws = (char*)d_ws;
  unsigned short* W1b = (unsigned short*)(ws);
  unsigned short* W2b = (unsigned short*)(ws + 524288);
  float* sc1 = (float*)(ws + 1048576);
  float* sh1 = sc1 + 512;
  float* sc2 = sh1 + 512;
  float* sh2 = sc2 + 512;
  unsigned short* CWt = (unsigned short*)(ws + 1064960);
  unsigned short* CWc = (unsigned short*)(ws + 1064960 + 114688);
  unsigned short* X2 = (unsigned short*)(ws + (1 << 21));
  unsigned short* X3 = X2 + (size_t)NBATCH * DD * HW;

  prep_kernel<<<1024, 256, 0, stream>>>(W1, W2, bn1s, bn1b, bn1m, bn1v,
                                        bn2s, bn2b, bn2m, bn2v,
                                        W1b, W2b, sc1, sh1, sc2, sh2);
  prep_cw<<<256, 256, 0, stream>>>(cw1, cw2, cw3, CWt, CWc);

  dim3 gg(HW / 128, DD / 128, NBATCH);
  gemm_bn<0><<<gg, 256, 0, stream>>>((const void*)X,  W1b, sc1, sh1, X2);
  gemm_bn<1><<<gg, 256, 0, stream>>>((const void*)X2, W2b, sc2, sh2, X3);

  dim3 gv(HW / 64, NBATCH);   // (144, 8)
  vq_mfma<<<gv, 256, 0, stream>>>(X, X2, X3, CWt, CWc, g1, g2, g3, (float*)d_out);
}